// Round 1
// baseline (419.257 us; speedup 1.0000x reference)
//
#include <hip/hip_runtime.h>

typedef unsigned short u16;
typedef unsigned int   u32;
typedef __attribute__((ext_vector_type(8))) short bf16x8;
typedef __attribute__((ext_vector_type(4))) float f32x4;

#define STR_XS 200   // u16/row: 400 B (16B-mult, bank stride 4 -> 2-way free)
#define STR_LB 68    // f32/row: 272 B
#define STR_Q  72    // u16/row: 144 B (16B-mult)

// Persistent preprocessed constants (rewritten every launch by prep kernel)
__device__ u16   g_wq[576 * 192];   // qkv_w bf16 [o][ci]
__device__ u16   g_wp[192 * 192];   // proj_w bf16 [o][ci]
__device__ float g_bh[6 * 64 * 64]; // rel bias expanded [h][m][n]
__device__ float g_dwt[10 * 576];   // dw weights [tap 0..8][o], tap 9 = dw_b

// round-half-up bf16 (vs RNE: differs only at exact ties, 1 ulp)
__device__ __forceinline__ u32 pkbf(float lo, float hi) {
    return __builtin_amdgcn_perm(__float_as_uint(hi) + 0x8000u,
                                 __float_as_uint(lo) + 0x8000u, 0x07060302u);
}
__device__ __forceinline__ u16 sbf(float f) {
    return (u16)((__float_as_uint(f) + 0x8000u) >> 16);
}

__global__ __launch_bounds__(256) void prep(
    const float* __restrict__ qkv_w, const float* __restrict__ proj_w,
    const float* __restrict__ btab, const float* __restrict__ dw_w,
    const float* __restrict__ dw_b)
{
    int i = blockIdx.x * 256 + threadIdx.x;
    if (i < 110592) { g_wq[i] = sbf(qkv_w[i]); return; }
    i -= 110592;
    if (i < 36864) { g_wp[i] = sbf(proj_w[i]); return; }
    i -= 36864;
    if (i < 24576) {
        int h = i >> 12, m = (i >> 6) & 63, n = i & 63;
        int ry = (m >> 3) - (n >> 3) + 7, rx = (m & 7) - (n & 7) + 7;
        g_bh[i] = btab[(ry * 15 + rx) * 6 + h];
        return;
    }
    i -= 24576;
    if (i < 5760) {
        int tap = i / 576, o = i - tap * 576;
        g_dwt[i] = (tap < 9) ? dw_w[o * 9 + tap] : dw_b[o];
    }
}

// One block per window. 256 threads = 4 waves. LDS 79,872 B -> 2 blocks/CU.
__global__ __launch_bounds__(256, 2) void wattn(
    const float* __restrict__ x, const float* __restrict__ mask,
    const float* __restrict__ qkv_b, const float* __restrict__ temp,
    const float* __restrict__ proj_b, float* __restrict__ out, int nW)
{
    const int b    = blockIdx.x;
    const int tid  = threadIdx.x;
    const int lane = tid & 63;
    const int wid  = __builtin_amdgcn_readfirstlane(tid >> 6);
    const int quad = lane >> 4, l15 = lane & 15;

    __shared__ u16   xs[64 * STR_XS];   // 25600 B  x bf16 [pix][ch]
    __shared__ float arena[64 * STR_LB];// 17408 B  conv1 fp32 / wave-private P / epilogue
    __shared__ u16   qh[64 * STR_Q];    //  9216 B  [pix][ch64]
    __shared__ u16   kh[64 * STR_Q];
    __shared__ u16   vh[64 * STR_Q];    //           [ch64][pix]
    __shared__ u16   oh[64 * STR_Q];    //           [pix][ch64]

    // ---- stage x -> xs (bf16) ----
    {
        const float* xb = x + (size_t)b * 12288;
        #pragma unroll
        for (int r = 0; r < 12; ++r) {
            int i4 = tid + r * 256;
            int pp = i4 / 48, c0 = (i4 % 48) * 4;
            float4 v = *(const float4*)(xb + pp * 192 + c0);
            u32* d = (u32*)&xs[pp * STR_XS + c0];
            d[0] = pkbf(v.x, v.y);
            d[1] = pkbf(v.z, v.w);
        }
    }

    const float* gmask = mask + (size_t)(b % nW) * 4096;
    const int p  = wid * 16 + l15;          // pixel owned in dw phase
    const int py = p >> 3, px = p & 7;

    f32x4 accP[12];
    #pragma unroll
    for (int i = 0; i < 12; ++i) accP[i] = f32x4{0.f, 0.f, 0.f, 0.f};

    for (int it = 0; it < 3; ++it) {
        // ======== q,k,v chunks (64 ch = head pair it*2, it*2+1) ========
        for (int g = 0; g < 3; ++g) {
            const int obase = g * 192 + it * 64;
            __syncthreads();   // arena write-safe (prev readers done)
            // ---- conv1 1x1 chunk: N-split, col tile = wid ----
            {
                f32x4 C[4];
                #pragma unroll
                for (int mt = 0; mt < 4; ++mt) C[mt] = f32x4{0.f, 0.f, 0.f, 0.f};
                const u16* wb = g_wq + (size_t)(obase + wid * 16 + l15) * 192;
                #pragma unroll
                for (int kf = 0; kf < 6; ++kf) {
                    bf16x8 bw = *(const bf16x8*)(wb + kf * 32 + quad * 8);
                    #pragma unroll
                    for (int mt = 0; mt < 4; ++mt) {
                        bf16x8 a = *(const bf16x8*)&xs[(mt * 16 + l15) * STR_XS + kf * 32 + quad * 8];
                        C[mt] = __builtin_amdgcn_mfma_f32_16x16x32_bf16(a, bw, C[mt], 0, 0, 0);
                    }
                }
                float qb = qkv_b[obase + wid * 16 + l15];
                #pragma unroll
                for (int mt = 0; mt < 4; ++mt)
                    #pragma unroll
                    for (int r = 0; r < 4; ++r)
                        arena[(mt * 16 + quad * 4 + r) * STR_LB + wid * 16 + l15] = C[mt][r] + qb;
            }
            __syncthreads();   // conv1 out ready
            // ---- depthwise 3x3: pixel = p, ch = quad*16.. ----
            const int c0 = quad * 16;
            const float* dwt = g_dwt + obase + c0;
            float dwv[16];
            {
                const float* bs = dwt + 9 * 576;
                *(f32x4*)&dwv[0]  = *(const f32x4*)(bs);
                *(f32x4*)&dwv[4]  = *(const f32x4*)(bs + 4);
                *(f32x4*)&dwv[8]  = *(const f32x4*)(bs + 8);
                *(f32x4*)&dwv[12] = *(const f32x4*)(bs + 12);
            }
            #pragma unroll
            for (int dy = -1; dy <= 1; ++dy) {
                int yy = py + dy;
                if ((unsigned)yy < 8u) {
                    #pragma unroll
                    for (int dx = -1; dx <= 1; ++dx) {
                        int xx = px + dx;
                        if ((unsigned)xx < 8u) {
                            const float* src = &arena[(yy * 8 + xx) * STR_LB + c0];
                            const float* wt  = dwt + ((dy + 1) * 3 + dx + 1) * 576;
                            float nb[16], wv[16];
                            *(f32x4*)&nb[0]  = *(const f32x4*)(src);
                            *(f32x4*)&nb[4]  = *(const f32x4*)(src + 4);
                            *(f32x4*)&nb[8]  = *(const f32x4*)(src + 8);
                            *(f32x4*)&nb[12] = *(const f32x4*)(src + 12);
                            *(f32x4*)&wv[0]  = *(const f32x4*)(wt);
                            *(f32x4*)&wv[4]  = *(const f32x4*)(wt + 4);
                            *(f32x4*)&wv[8]  = *(const f32x4*)(wt + 8);
                            *(f32x4*)&wv[12] = *(const f32x4*)(wt + 12);
                            #pragma unroll
                            for (int j = 0; j < 16; ++j)
                                dwv[j] = fmaf(nb[j], wv[j], dwv[j]);
                        }
                    }
                }
            }
            if (g < 2) {
                // in-wave L2 norm over the head's 32 ch (quad-pair exchange)
                float ss = 0.f;
                #pragma unroll
                for (int j = 0; j < 16; ++j) ss = fmaf(dwv[j], dwv[j], ss);
                ss += __shfl_xor(ss, 16, 64);
                float tf = (g == 0) ? temp[it * 2 + (quad >> 1)] : 1.f;
                float s = tf / fmaxf(sqrtf(ss), 1e-12f);
                u16* dst = (g == 0) ? qh : kh;
                u32* d = (u32*)&dst[p * STR_Q + c0];
                #pragma unroll
                for (int j = 0; j < 8; ++j)
                    d[j] = pkbf(dwv[2 * j] * s, dwv[2 * j + 1] * s);
            } else {
                #pragma unroll
                for (int j = 0; j < 16; ++j)
                    vh[(c0 + j) * STR_Q + p] = sbf(dwv[j]);
            }
        }
        __syncthreads();   // q,k,v ready; arena free for P scratch

        // ======== attention: wave owns q-rows wid*16.., no barriers ========
        u16* Pw = ((u16*)arena) + wid * (16 * STR_Q);   // wave-private P
        for (int h2 = 0; h2 < 2; ++h2) {
            const int h = it * 2 + h2, ch0 = h2 * 32;
            f32x4 S[4];
            #pragma unroll
            for (int nt = 0; nt < 4; ++nt) S[nt] = f32x4{0.f, 0.f, 0.f, 0.f};
            bf16x8 aq = *(const bf16x8*)&qh[(wid * 16 + l15) * STR_Q + ch0 + quad * 8];
            #pragma unroll
            for (int nt = 0; nt < 4; ++nt) {
                bf16x8 bk = *(const bf16x8*)&kh[(nt * 16 + l15) * STR_Q + ch0 + quad * 8];
                S[nt] = __builtin_amdgcn_mfma_f32_16x16x32_bf16(aq, bk, S[nt], 0, 0, 0);
            }
            const float* bh = g_bh + h * 4096 + (wid * 16 + quad * 4) * 64 + l15;
            const float* gm = gmask + (wid * 16 + quad * 4) * 64 + l15;
            #pragma unroll
            for (int nt = 0; nt < 4; ++nt)
                #pragma unroll
                for (int r = 0; r < 4; ++r)
                    S[nt][r] += bh[r * 64 + nt * 16] + gm[r * 64 + nt * 16];
            // in-register softmax per row (reduce over l15)
            #pragma unroll
            for (int r = 0; r < 4; ++r) {
                float mx = fmaxf(fmaxf(S[0][r], S[1][r]), fmaxf(S[2][r], S[3][r]));
                mx = fmaxf(mx, __shfl_xor(mx, 1, 64));
                mx = fmaxf(mx, __shfl_xor(mx, 2, 64));
                mx = fmaxf(mx, __shfl_xor(mx, 4, 64));
                mx = fmaxf(mx, __shfl_xor(mx, 8, 64));
                float e0 = __expf(S[0][r] - mx), e1 = __expf(S[1][r] - mx);
                float e2 = __expf(S[2][r] - mx), e3 = __expf(S[3][r] - mx);
                float sm = (e0 + e1) + (e2 + e3);
                sm += __shfl_xor(sm, 1, 64);
                sm += __shfl_xor(sm, 2, 64);
                sm += __shfl_xor(sm, 4, 64);
                sm += __shfl_xor(sm, 8, 64);
                float iv = 1.f / sm;
                u16* pr = Pw + (quad * 4 + r) * STR_Q + l15;
                pr[0]  = sbf(e0 * iv);
                pr[16] = sbf(e1 * iv);
                pr[32] = sbf(e2 * iv);
                pr[48] = sbf(e3 * iv);
            }
            // PV (P read back wave-synchronously)
            f32x4 O[2];
            O[0] = f32x4{0.f, 0.f, 0.f, 0.f};
            O[1] = f32x4{0.f, 0.f, 0.f, 0.f};
            #pragma unroll
            for (int kf = 0; kf < 2; ++kf) {
                bf16x8 ap = *(const bf16x8*)(Pw + l15 * STR_Q + kf * 32 + quad * 8);
                #pragma unroll
                for (int nt = 0; nt < 2; ++nt) {
                    bf16x8 bv = *(const bf16x8*)&vh[(ch0 + nt * 16 + l15) * STR_Q + kf * 32 + quad * 8];
                    O[nt] = __builtin_amdgcn_mfma_f32_16x16x32_bf16(ap, bv, O[nt], 0, 0, 0);
                }
            }
            #pragma unroll
            for (int nt = 0; nt < 2; ++nt)
                #pragma unroll
                for (int r = 0; r < 4; ++r)
                    oh[(wid * 16 + quad * 4 + r) * STR_Q + ch0 + nt * 16 + l15] = sbf(O[nt][r]);
        }
        __syncthreads();   // oh ready (also: all P reads done before next arena use)

        // ======== proj partial: acc += O(64 ch) @ Wp ========
        #pragma unroll
        for (int kf = 0; kf < 2; ++kf) {
            bf16x8 A4[4];
            #pragma unroll
            for (int mt = 0; mt < 4; ++mt)
                A4[mt] = *(const bf16x8*)&oh[(mt * 16 + l15) * STR_Q + kf * 32 + quad * 8];
            #pragma unroll
            for (int nt = 0; nt < 3; ++nt) {
                bf16x8 bw = *(const bf16x8*)(g_wp + (size_t)(wid * 48 + nt * 16 + l15) * 192 + it * 64 + kf * 32 + quad * 8);
                #pragma unroll
                for (int mt = 0; mt < 4; ++mt)
                    accP[nt * 4 + mt] = __builtin_amdgcn_mfma_f32_16x16x32_bf16(A4[mt], bw, accP[nt * 4 + mt], 0, 0, 0);
            }
        }
    }

    // ======== epilogue: transpose via arena, coalesced NCHW store ========
    __syncthreads();
    {
        float* ob = out + (size_t)b * 12288;
        for (int rr = 0; rr < 3; ++rr) {
            float pb = proj_b[wid * 48 + rr * 16 + l15];
            #pragma unroll
            for (int mt = 0; mt < 4; ++mt)
                #pragma unroll
                for (int r = 0; r < 4; ++r)
                    arena[(wid * 16 + l15) * STR_LB + mt * 16 + quad * 4 + r] = accP[rr * 4 + mt][r] + pb;
            __syncthreads();
            {
                int ol = tid >> 2, sub = tid & 3;
                int ocg = (ol >> 4) * 48 + rr * 16 + (ol & 15);
                const float4* srp = (const float4*)&arena[ol * STR_LB + sub * 16];
                float4* dst = (float4*)(ob + (size_t)ocg * 64 + sub * 16);
                dst[0] = srp[0]; dst[1] = srp[1]; dst[2] = srp[2]; dst[3] = srp[3];
            }
            __syncthreads();
        }
    }
}

extern "C" void kernel_launch(void* const* d_in, const int* in_sizes, int n_in,
                              void* d_out, int out_size, void* d_ws, size_t ws_size,
                              hipStream_t stream)
{
    const float* x      = (const float*)d_in[0];
    const float* mask   = (const float*)d_in[1];
    const float* qkv_w  = (const float*)d_in[2];
    const float* qkv_b  = (const float*)d_in[3];
    const float* dw_w   = (const float*)d_in[4];
    const float* dw_b   = (const float*)d_in[5];
    const float* proj_w = (const float*)d_in[6];
    const float* proj_b = (const float*)d_in[7];
    const float* temp   = (const float*)d_in[8];
    const float* btab   = (const float*)d_in[9];
    float* out = (float*)d_out;

    const int b  = in_sizes[0] / 12288;   // 2048
    const int nW = in_sizes[1] / 4096;    // 512

    prep<<<dim3(695), dim3(256), 0, stream>>>(qkv_w, proj_w, btab, dw_w, dw_b);
    wattn<<<dim3(b), dim3(256), 0, stream>>>(x, mask, qkv_b, temp, proj_b, out, nW);
}